// Round 1
// baseline (72.300 us; speedup 1.0000x reference)
//
#include <hip/hip_runtime.h>
#include <hip/hip_bf16.h>
#include <math.h>

// out[n,:] = s1 .* FWHT( (u/4096) .* FWHT( s2 .* x[n,:] ) )
// with u = g_mu + softplus(g_rho)*epsilon, FWHT = unnormalized Walsh-Hadamard.
// D = 4096 = 16^3: six radix-16 register passes + four LDS digit rotations.

#define WHVI_D 4096
#define WHVI_THREADS 256
#define S2STRIDE 272  // words; 272%32=16 -> combined with *17 inner stride, transposes are ~conflict-free
// logical (c2,c1,c0), c2,c1,c0 in [0,16) -> word addr c2*272 + c1*17 + c0 (injective: 15*17+15=270<272)

__device__ __forceinline__ void fwht16(float v[16]) {
#pragma unroll
    for (int s = 1; s < 16; s <<= 1) {
#pragma unroll
        for (int i = 0; i < 16; ++i) {
            if ((i & s) == 0) {
                float a = v[i];
                float b = v[i | s];
                v[i] = a + b;
                v[i | s] = a - b;
            }
        }
    }
}

__global__ __launch_bounds__(WHVI_THREADS)
void whvi_fwht_kernel(const float* __restrict__ x,
                      const float* __restrict__ s1,
                      const float* __restrict__ s2,
                      const float* __restrict__ g_mu,
                      const float* __restrict__ g_rho,
                      const float* __restrict__ g_eps,
                      float* __restrict__ out,
                      int nrows) {
    __shared__ float lds[16 * S2STRIDE];

    const int t = threadIdx.x;      // 0..255
    const int P = t >> 4;           // 0..15
    const int Q = t & 15;           // 0..15
    const int row = blockIdx.x;
    if (row >= nrows) return;

    const float* xr = x + (size_t)row * WHVI_D;
    float* outr = out + (size_t)row * WHVI_D;

    float v[16];

    // ---- load x, scale by s2: element i = 16*t + j = (d2=P, d1=Q, d0=j) ----
    {
        const float4* xv = reinterpret_cast<const float4*>(xr + t * 16);
        const float4* sv = reinterpret_cast<const float4*>(s2 + t * 16);
#pragma unroll
        for (int c = 0; c < 4; ++c) {
            float4 xx = xv[c];
            float4 ss = sv[c];
            v[4 * c + 0] = xx.x * ss.x;
            v[4 * c + 1] = xx.y * ss.y;
            v[4 * c + 2] = xx.z * ss.z;
            v[4 * c + 3] = xx.w * ss.w;
        }
    }

    // ---- pass 1: transform d0 (registers) ----
    fwht16(v);

    // ---- rotation 1: write (P,Q,j), read (P,j,Q) -> regs become d1 ----
#pragma unroll
    for (int j = 0; j < 16; ++j) lds[P * S2STRIDE + Q * 17 + j] = v[j];
    __syncthreads();
#pragma unroll
    for (int j = 0; j < 16; ++j) v[j] = lds[P * S2STRIDE + j * 17 + Q];

    // ---- pass 2: transform d1 ----
    fwht16(v);

    // ---- rotation 2: write back to SAME per-thread addrs (no barrier needed),
    //      then read (j,P,Q) -> regs become d2 ----
#pragma unroll
    for (int j = 0; j < 16; ++j) lds[P * S2STRIDE + j * 17 + Q] = v[j];
    __syncthreads();
#pragma unroll
    for (int j = 0; j < 16; ++j) v[j] = lds[j * S2STRIDE + P * 17 + Q];

    // ---- pass 3: transform d2 -> v[j] = FWHT(s2*x)[j*256 + t] ----
    fwht16(v);

    // ---- u multiply: u[j*256 + t], coalesced per j; fold 1/4096 here ----
#pragma unroll
    for (int j = 0; j < 16; ++j) {
        int idx = j * 256 + t;
        float mu = g_mu[idx];
        float rho = g_rho[idx];
        float ep = g_eps[idx];
        // softplus(rho) = max(rho,0) + log1p(exp(-|rho|)); fast intrinsics are
        // accurate to ~1e-7 rel, far below the 0.45 abs tolerance.
        float sp = fmaxf(rho, 0.0f) + __logf(1.0f + __expf(-fabsf(rho)));
        float u = (mu + sp * ep) * (1.0f / 4096.0f);
        v[j] *= u;
    }

    // ---- pass 4: transform f2 (regs already hold digit-2 of the new vector) ----
    fwht16(v);

    // ---- rotation 3: write (j,P,Q) (same addrs as rotation-2 read -> no
    //      barrier before), read (P,j,Q) -> regs become f1 ----
#pragma unroll
    for (int j = 0; j < 16; ++j) lds[j * S2STRIDE + P * 17 + Q] = v[j];
    __syncthreads();
#pragma unroll
    for (int j = 0; j < 16; ++j) v[j] = lds[P * S2STRIDE + j * 17 + Q];

    // ---- pass 5: transform f1 ----
    fwht16(v);

    // ---- rotation 4: write back same addrs, read (P,Q,j) -> regs become f0 ----
#pragma unroll
    for (int j = 0; j < 16; ++j) lds[P * S2STRIDE + j * 17 + Q] = v[j];
    __syncthreads();
#pragma unroll
    for (int j = 0; j < 16; ++j) v[j] = lds[P * S2STRIDE + Q * 17 + j];

    // ---- pass 6: transform f0 -> final element o = 16*t + j ----
    fwht16(v);

    // ---- s1 scale + store, vectorized ----
    {
        const float4* sv = reinterpret_cast<const float4*>(s1 + t * 16);
        float4* ov = reinterpret_cast<float4*>(outr + t * 16);
#pragma unroll
        for (int c = 0; c < 4; ++c) {
            float4 ss = sv[c];
            float4 oo;
            oo.x = v[4 * c + 0] * ss.x;
            oo.y = v[4 * c + 1] * ss.y;
            oo.z = v[4 * c + 2] * ss.z;
            oo.w = v[4 * c + 3] * ss.w;
            ov[c] = oo;
        }
    }
}

extern "C" void kernel_launch(void* const* d_in, const int* in_sizes, int n_in,
                              void* d_out, int out_size, void* d_ws, size_t ws_size,
                              hipStream_t stream) {
    const float* x     = (const float*)d_in[0];
    const float* s1    = (const float*)d_in[1];
    const float* s2    = (const float*)d_in[2];
    const float* g_mu  = (const float*)d_in[3];
    const float* g_rho = (const float*)d_in[4];
    const float* g_eps = (const float*)d_in[5];
    // d_in[6] is H — unused; the FWHT realizes it exactly.
    float* out = (float*)d_out;

    const int nrows = in_sizes[0] / WHVI_D;  // 8192
    whvi_fwht_kernel<<<nrows, WHVI_THREADS, 0, stream>>>(
        x, s1, s2, g_mu, g_rho, g_eps, out, nrows);
}